// Round 1
// baseline (431.139 us; speedup 1.0000x reference)
//
#include <hip/hip_runtime.h>
#include <math.h>
#include <stdint.h>

// Problem constants: B=8, N=2048, D=512, H=16, dk=32
// q = x@Wq^T; k = x@Wk^T; v = x@Wv^T            [t=16384, c=512]
// dw[b,i,j] = exp(-alpha*11*dis[b,i,j])
// w1[b,j,c] = sum_i dw[b,i,j]*exp(k)[b,i,c]*v[b,i,c]
// w2[b,j,c] = sum_i dw[b,i,j]*exp(k)[b,i,c]
// out[b,j,c] = sigmoid(q)[b,j,c] * w1/w2

typedef __bf16 bf16_t;
typedef __attribute__((ext_vector_type(4))) __bf16 bf16x4;
typedef __attribute__((ext_vector_type(8))) __bf16 bf16x8;
typedef __attribute__((ext_vector_type(4))) float f32x4;

#define MFMA_BF16(a, b, c) __builtin_amdgcn_mfma_f32_16x16x32_bf16((a), (b), (c), 0, 0, 0)

// global -> LDS direct copy, 16B per lane. LDS dest = (wave-uniform base) + lane*16.
static __device__ __forceinline__ void async_ld16(const bf16_t* g, bf16_t* lds) {
  __builtin_amdgcn_global_load_lds(
      reinterpret_cast<__attribute__((address_space(1))) unsigned int*>(
          reinterpret_cast<uintptr_t>(g)),
      reinterpret_cast<__attribute__((address_space(3))) unsigned int*>(
          reinterpret_cast<uintptr_t>(lds)),
      16, 0, 0);
}

// ---------------- fp32 -> bf16 conversion (vectorized x4) ----------------
__global__ __launch_bounds__(256) void cvt_bf16_k(const float* __restrict__ src,
                                                  bf16_t* __restrict__ dst, int n4) {
  int i = blockIdx.x * 256 + threadIdx.x;
  if (i >= n4) return;
  f32x4 f = ((const f32x4*)src)[i];
  bf16x4 o;
  o[0] = (bf16_t)f[0]; o[1] = (bf16_t)f[1]; o[2] = (bf16_t)f[2]; o[3] = (bf16_t)f[3];
  ((bf16x4*)dst)[i] = o;
}

// ---------------- projection GEMM: C[16384,1536] = x_bf @ Wall^T ----------------
// Wall rows: [0,512)=Wq, [512,1024)=Wk, [1024,1536)=Wv (row-major [out_c, in] == B^T layout).
// Epilogue by column block: q -> sigmoid -> qs (fp32, stored in d_out); k,v -> bf16.
__global__ __launch_bounds__(256) void proj_gemm(const bf16_t* __restrict__ A,
                                                 const bf16_t* __restrict__ W,
                                                 float* __restrict__ qs,
                                                 bf16_t* __restrict__ kbf,
                                                 bf16_t* __restrict__ vbf) {
  __shared__ bf16_t As[128 * 32];
  __shared__ bf16_t Bs[128 * 32];
  const int K = 512;
  const int tid = threadIdx.x;
  const int wave = tid >> 6, lane = tid & 63;
  const int lrow = lane >> 2, lk = (lane & 3) * 8;
  const int l15 = lane & 15, quad = lane >> 4;
  const int m_blk = blockIdx.x, n_blk = blockIdx.y;

  f32x4 acc[2][8];
#pragma unroll
  for (int i = 0; i < 2; ++i)
#pragma unroll
    for (int j = 0; j < 8; ++j) acc[i][j] = (f32x4){0.f, 0.f, 0.f, 0.f};

  for (int k0 = 0; k0 < K; k0 += 32) {
#pragma unroll
    for (int s = 0; s < 2; ++s) {
      int row = wave * 32 + s * 16 + lrow;
      async_ld16(A + (size_t)(m_blk * 128 + row) * K + k0 + lk,
                 &As[(wave * 32 + s * 16) * 32]);
      async_ld16(W + (size_t)(n_blk * 128 + row) * K + k0 + lk,
                 &Bs[(wave * 32 + s * 16) * 32]);
    }
    __syncthreads();
    bf16x8 a0 = *(const bf16x8*)&As[(wave * 32 + l15) * 32 + quad * 8];
    bf16x8 a1 = *(const bf16x8*)&As[(wave * 32 + 16 + l15) * 32 + quad * 8];
#pragma unroll
    for (int tn = 0; tn < 8; ++tn) {
      bf16x8 bfr = *(const bf16x8*)&Bs[(tn * 16 + l15) * 32 + quad * 8];
      acc[0][tn] = MFMA_BF16(a0, bfr, acc[0][tn]);
      acc[1][tn] = MFMA_BF16(a1, bfr, acc[1][tn]);
    }
    __syncthreads();
  }

  const int region = n_blk >> 2;           // 0: q, 1: k, 2: v
  const int c_loc = (n_blk & 3) * 128;     // column within the 512-wide region
#pragma unroll
  for (int tm = 0; tm < 2; ++tm) {
#pragma unroll
    for (int tn = 0; tn < 8; ++tn) {
      int c = c_loc + tn * 16 + l15;
#pragma unroll
      for (int r = 0; r < 4; ++r) {
        int t = m_blk * 128 + wave * 32 + tm * 16 + quad * 4 + r;
        size_t idx = (size_t)t * 512 + c;
        float val = acc[tm][tn][r];
        if (region == 0) {
          qs[idx] = 1.0f / (1.0f + __expf(-val));
        } else if (region == 1) {
          kbf[idx] = (bf16_t)val;
        } else {
          vbf[idx] = (bf16_t)val;
        }
      }
    }
  }
}

// ---------------- transform + transpose: kwT[b,c,i]=exp(k), kwvT[b,c,i]=exp(k)*v ----------------
__global__ __launch_bounds__(256) void transform_kv(const bf16_t* __restrict__ kbf,
                                                    const bf16_t* __restrict__ vbf,
                                                    bf16_t* __restrict__ kwT,
                                                    bf16_t* __restrict__ kwvT) {
  __shared__ bf16_t t1[64 * 65];
  __shared__ bf16_t t2[64 * 65];
  const int i0 = blockIdx.x * 64, c0 = blockIdx.y * 64, b = blockIdx.z;
  const int tid = threadIdx.x;
  const int rr = tid >> 4, cc = (tid & 15) * 4;
#pragma unroll
  for (int p = 0; p < 4; ++p) {
    int i = rr + p * 16;
    size_t g = ((size_t)(b * 2048 + i0 + i)) * 512 + c0 + cc;
    bf16x4 kk = *(const bf16x4*)&kbf[g];
    bf16x4 vv = *(const bf16x4*)&vbf[g];
#pragma unroll
    for (int e = 0; e < 4; ++e) {
      float kw = __expf((float)kk[e]);
      float kv = kw * (float)vv[e];
      t1[(cc + e) * 65 + i] = (bf16_t)kw;
      t2[(cc + e) * 65 + i] = (bf16_t)kv;
    }
  }
  __syncthreads();
#pragma unroll
  for (int p = 0; p < 4; ++p) {
    int c = rr + p * 16;
    size_t g = ((size_t)(b * 512 + c0 + c)) * 2048 + i0 + cc;
    bf16x4 o1, o2;
#pragma unroll
    for (int e = 0; e < 4; ++e) {
      o1[e] = t1[c * 65 + cc + e];
      o2[e] = t2[c * 65 + cc + e];
    }
    *(bf16x4*)&kwT[g] = o1;
    *(bf16x4*)&kwvT[g] = o2;
  }
}

// ---------------- dwT[b,j,i] = bf16(exp(-alpha*11*dis[b,i,j])) ----------------
__global__ __launch_bounds__(256) void make_dwT(const float* __restrict__ dis,
                                                bf16_t* __restrict__ dwT,
                                                const float* __restrict__ alpha) {
  __shared__ bf16_t t[64 * 65];
  const float coef = -alpha[0] * 11.0f;  // log2(2048) == 11
  const int j0 = blockIdx.x * 64, i0 = blockIdx.y * 64, b = blockIdx.z;
  const int tid = threadIdx.x;
  const int rr = tid >> 4, cc = (tid & 15) * 4;
#pragma unroll
  for (int p = 0; p < 4; ++p) {
    int i = rr + p * 16;
    f32x4 d = *(const f32x4*)&dis[((size_t)(b * 2048 + i0 + i)) * 2048 + j0 + cc];
#pragma unroll
    for (int e = 0; e < 4; ++e) t[(cc + e) * 65 + i] = (bf16_t)__expf(coef * d[e]);
  }
  __syncthreads();
#pragma unroll
  for (int p = 0; p < 4; ++p) {
    int j = rr + p * 16;
    bf16x4 o;
#pragma unroll
    for (int e = 0; e < 4; ++e) o[e] = t[j * 65 + cc + e];
    *(bf16x4*)&dwT[((size_t)(b * 2048 + j0 + j)) * 2048 + i0 + cc] = o;
  }
}

// ---------------- main batched GEMM + fused epilogue ----------------
// Per batch b: C[j, n] over n in [0,128): n<64 -> w1 (kwvT rows c0+n), n>=64 -> w2 (kwT rows).
// out[b,j,c] = qs[b,j,c] * w1/w2  (qs lives in `out` already).
__global__ __launch_bounds__(256) void main_gemm(const bf16_t* __restrict__ dwT,
                                                 const bf16_t* __restrict__ kwvT,
                                                 const bf16_t* __restrict__ kwT,
                                                 float* __restrict__ out) {
  __shared__ bf16_t As[128 * 32];
  __shared__ bf16_t Bs[128 * 32];
  const int K = 2048;
  const int tid = threadIdx.x;
  const int wave = tid >> 6, lane = tid & 63;
  const int lrow = lane >> 2, lk = (lane & 3) * 8;
  const int l15 = lane & 15, quad = lane >> 4;
  const int m_blk = blockIdx.x, cb = blockIdx.y, b = blockIdx.z;

  const bf16_t* Ab = dwT + ((size_t)b * 2048 + m_blk * 128) * K;
  const bf16_t* B1 = kwvT + ((size_t)b * 512 + cb * 64) * K;
  const bf16_t* B2 = kwT + ((size_t)b * 512 + cb * 64) * K;

  f32x4 acc[2][8];
#pragma unroll
  for (int i = 0; i < 2; ++i)
#pragma unroll
    for (int j = 0; j < 8; ++j) acc[i][j] = (f32x4){0.f, 0.f, 0.f, 0.f};

  for (int k0 = 0; k0 < K; k0 += 32) {
#pragma unroll
    for (int s = 0; s < 2; ++s) {
      int row = wave * 32 + s * 16 + lrow;
      async_ld16(Ab + (size_t)row * K + k0 + lk, &As[(wave * 32 + s * 16) * 32]);
      const bf16_t* bsrc = (row < 64) ? (B1 + (size_t)row * K) : (B2 + (size_t)(row - 64) * K);
      async_ld16(bsrc + k0 + lk, &Bs[(wave * 32 + s * 16) * 32]);
    }
    __syncthreads();
    bf16x8 a0 = *(const bf16x8*)&As[(wave * 32 + l15) * 32 + quad * 8];
    bf16x8 a1 = *(const bf16x8*)&As[(wave * 32 + 16 + l15) * 32 + quad * 8];
#pragma unroll
    for (int tn = 0; tn < 8; ++tn) {
      bf16x8 bfr = *(const bf16x8*)&Bs[(tn * 16 + l15) * 32 + quad * 8];
      acc[0][tn] = MFMA_BF16(a0, bfr, acc[0][tn]);
      acc[1][tn] = MFMA_BF16(a1, bfr, acc[1][tn]);
    }
    __syncthreads();
  }

#pragma unroll
  for (int tm = 0; tm < 2; ++tm) {
#pragma unroll
    for (int tc = 0; tc < 4; ++tc) {
      f32x4 w1 = acc[tm][tc];
      f32x4 w2 = acc[tm][tc + 4];
      int c = cb * 64 + tc * 16 + l15;
#pragma unroll
      for (int r = 0; r < 4; ++r) {
        int j = m_blk * 128 + wave * 32 + tm * 16 + quad * 4 + r;
        size_t idx = ((size_t)b * 2048 + j) * 512 + c;
        float sq = out[idx];  // sigmoid(q), written by proj_gemm
        out[idx] = sq * (w1[r] / w2[r]);
      }
    }
  }
}

extern "C" void kernel_launch(void* const* d_in, const int* in_sizes, int n_in,
                              void* d_out, int out_size, void* d_ws, size_t ws_size,
                              hipStream_t stream) {
  const float* x = (const float*)d_in[0];
  const float* dis = (const float*)d_in[1];
  const float* Wq = (const float*)d_in[2];
  const float* Wk = (const float*)d_in[3];
  const float* Wv = (const float*)d_in[4];
  const float* alpha = (const float*)d_in[5];
  float* out = (float*)d_out;

  char* p = (char*)d_ws;
  bf16_t* x_bf = (bf16_t*)p;  p += (size_t)16384 * 512 * 2;       // 16 MB
  bf16_t* Wall = (bf16_t*)p;  p += (size_t)1536 * 512 * 2;        // 1.5 MB
  bf16_t* kbf  = (bf16_t*)p;  p += (size_t)16384 * 512 * 2;       // 16 MB
  bf16_t* vbf  = (bf16_t*)p;  p += (size_t)16384 * 512 * 2;       // 16 MB
  bf16_t* kwT  = (bf16_t*)p;  p += (size_t)8 * 512 * 2048 * 2;    // 16 MB
  bf16_t* kwvT = (bf16_t*)p;  p += (size_t)8 * 512 * 2048 * 2;    // 16 MB
  bf16_t* dwT  = (bf16_t*)p;  p += (size_t)8 * 2048 * 2048 * 2;   // 64 MB
  if ((size_t)(p - (char*)d_ws) > ws_size) return;  // ws too small: fail visibly

  cvt_bf16_k<<<8192, 256, 0, stream>>>(x, x_bf, 2097152);
  cvt_bf16_k<<<256, 256, 0, stream>>>(Wq, Wall, 65536);
  cvt_bf16_k<<<256, 256, 0, stream>>>(Wk, Wall + 262144, 65536);
  cvt_bf16_k<<<256, 256, 0, stream>>>(Wv, Wall + 524288, 65536);
  proj_gemm<<<dim3(128, 12), 256, 0, stream>>>(x_bf, Wall, out, kbf, vbf);
  transform_kv<<<dim3(32, 8, 8), 256, 0, stream>>>(kbf, vbf, kwT, kwvT);
  make_dwT<<<dim3(32, 32, 8), 256, 0, stream>>>(dis, dwT, alpha);
  main_gemm<<<dim3(16, 8, 8), 256, 0, stream>>>(dwT, kwvT, kwT, out);
}

// Round 2
// 406.488 us; speedup vs baseline: 1.0606x; 1.0606x over previous
//
#include <hip/hip_runtime.h>
#include <math.h>
#include <stdint.h>

// Problem constants: B=8, N=2048, D=512, H=16, dk=32
// q = x@Wq^T; k = x@Wk^T; v = x@Wv^T            [t=16384, c=512]
// dw[b,i,j] = exp(-alpha*11*dis[b,i,j])
// w1[b,j,c] = sum_i dw[b,i,j]*exp(k)[b,i,c]*v[b,i,c]
// w2[b,j,c] = sum_i dw[b,i,j]*exp(k)[b,i,c]
// out[b,j,c] = sigmoid(q)[b,j,c] * w1/w2

typedef __bf16 bf16_t;
typedef __attribute__((ext_vector_type(4))) __bf16 bf16x4;
typedef __attribute__((ext_vector_type(8))) __bf16 bf16x8;
typedef __attribute__((ext_vector_type(4))) float f32x4;

#define MFMA_BF16(a, b, c) __builtin_amdgcn_mfma_f32_16x16x32_bf16((a), (b), (c), 0, 0, 0)

// global -> LDS direct copy, 16B per lane. LDS dest = (wave-uniform base) + lane*16.
static __device__ __forceinline__ void async_ld16(const bf16_t* g, bf16_t* lds) {
  __builtin_amdgcn_global_load_lds(
      reinterpret_cast<__attribute__((address_space(1))) unsigned int*>(
          reinterpret_cast<uintptr_t>(g)),
      reinterpret_cast<__attribute__((address_space(3))) unsigned int*>(
          reinterpret_cast<uintptr_t>(lds)),
      16, 0, 0);
}

// ---------------- fp32 -> bf16 conversion (vectorized x4) ----------------
__global__ __launch_bounds__(256) void cvt_bf16_k(const float* __restrict__ src,
                                                  bf16_t* __restrict__ dst, int n4) {
  int i = blockIdx.x * 256 + threadIdx.x;
  if (i >= n4) return;
  f32x4 f = ((const f32x4*)src)[i];
  bf16x4 o;
  o[0] = (bf16_t)f[0]; o[1] = (bf16_t)f[1]; o[2] = (bf16_t)f[2]; o[3] = (bf16_t)f[3];
  ((bf16x4*)dst)[i] = o;
}

// ---------------- fused projection GEMM ----------------
// Wall rows: [0,512)=Wq, [512,1024)=Wk, [1024,1536)=Wv (row-major [out_c, in]).
// n_blk 0..3: q tile -> sigmoid -> qs (fp32, stored in d_out).
// n_blk 4..7: k AND v tiles in one block -> kw=exp(k), kwv=kw*v -> LDS transpose ->
//             kwT[b,c,t], kwvT[b,c,t] (bf16), directly in main-GEMM operand layout.
__global__ __launch_bounds__(256) void proj_gemm(const bf16_t* __restrict__ A,
                                                 const bf16_t* __restrict__ W,
                                                 float* __restrict__ qs,
                                                 bf16_t* __restrict__ kwT,
                                                 bf16_t* __restrict__ kwvT) {
  __shared__ bf16_t As[128 * 32];
  __shared__ bf16_t Bs[2][128 * 32];
  __shared__ bf16_t Lk[4344];  // 32 x 128 transpose chunk, stride 136 (16B-aligned rows)
  __shared__ bf16_t Lv[4344];
  const int K = 512;
  const int tid = threadIdx.x;
  const int wave = tid >> 6, lane = tid & 63;
  const int lrow = lane >> 2, lk = (lane & 3) * 8;
  const int l15 = lane & 15, quad = lane >> 4;
  const int m_blk = blockIdx.x, n_blk = blockIdx.y;
  const bool is_q = (n_blk < 4);
  const int c_loc = (n_blk & 3) * 128;

  if (is_q) {
    // ---- q path: plain 128x128 GEMM vs Wq, sigmoid epilogue ----
    f32x4 acc[2][8];
#pragma unroll
    for (int i = 0; i < 2; ++i)
#pragma unroll
      for (int j = 0; j < 8; ++j) acc[i][j] = (f32x4){0.f, 0.f, 0.f, 0.f};

    for (int k0 = 0; k0 < K; k0 += 32) {
#pragma unroll
      for (int s = 0; s < 2; ++s) {
        int row = wave * 32 + s * 16 + lrow;
        async_ld16(A + (size_t)(m_blk * 128 + row) * K + k0 + lk,
                   &As[(wave * 32 + s * 16) * 32]);
        async_ld16(W + (size_t)(c_loc + row) * K + k0 + lk,
                   &Bs[0][(wave * 32 + s * 16) * 32]);
      }
      __syncthreads();
      bf16x8 a0 = *(const bf16x8*)&As[(wave * 32 + l15) * 32 + quad * 8];
      bf16x8 a1 = *(const bf16x8*)&As[(wave * 32 + 16 + l15) * 32 + quad * 8];
#pragma unroll
      for (int tn = 0; tn < 8; ++tn) {
        bf16x8 bfr = *(const bf16x8*)&Bs[0][(tn * 16 + l15) * 32 + quad * 8];
        acc[0][tn] = MFMA_BF16(a0, bfr, acc[0][tn]);
        acc[1][tn] = MFMA_BF16(a1, bfr, acc[1][tn]);
      }
      __syncthreads();
    }
#pragma unroll
    for (int tm = 0; tm < 2; ++tm)
#pragma unroll
      for (int tn = 0; tn < 8; ++tn) {
        int c = c_loc + tn * 16 + l15;
#pragma unroll
        for (int r = 0; r < 4; ++r) {
          int t = m_blk * 128 + wave * 32 + tm * 16 + quad * 4 + r;
          qs[(size_t)t * 512 + c] = 1.0f / (1.0f + __expf(-acc[tm][tn][r]));
        }
      }
  } else {
    // ---- kv path: two GEMMs sharing the A staging ----
    f32x4 acck[2][8], accv[2][8];
#pragma unroll
    for (int i = 0; i < 2; ++i)
#pragma unroll
      for (int j = 0; j < 8; ++j) {
        acck[i][j] = (f32x4){0.f, 0.f, 0.f, 0.f};
        accv[i][j] = (f32x4){0.f, 0.f, 0.f, 0.f};
      }
    const bf16_t* Wk = W + (size_t)(512 + c_loc) * K;
    const bf16_t* Wv = W + (size_t)(1024 + c_loc) * K;

    for (int k0 = 0; k0 < K; k0 += 32) {
#pragma unroll
      for (int s = 0; s < 2; ++s) {
        int row = wave * 32 + s * 16 + lrow;
        async_ld16(A + (size_t)(m_blk * 128 + row) * K + k0 + lk,
                   &As[(wave * 32 + s * 16) * 32]);
        async_ld16(Wk + (size_t)row * K + k0 + lk, &Bs[0][(wave * 32 + s * 16) * 32]);
        async_ld16(Wv + (size_t)row * K + k0 + lk, &Bs[1][(wave * 32 + s * 16) * 32]);
      }
      __syncthreads();
      bf16x8 a0 = *(const bf16x8*)&As[(wave * 32 + l15) * 32 + quad * 8];
      bf16x8 a1 = *(const bf16x8*)&As[(wave * 32 + 16 + l15) * 32 + quad * 8];
#pragma unroll
      for (int tn = 0; tn < 8; ++tn) {
        bf16x8 bk = *(const bf16x8*)&Bs[0][(tn * 16 + l15) * 32 + quad * 8];
        bf16x8 bv = *(const bf16x8*)&Bs[1][(tn * 16 + l15) * 32 + quad * 8];
        acck[0][tn] = MFMA_BF16(a0, bk, acck[0][tn]);
        acck[1][tn] = MFMA_BF16(a1, bk, acck[1][tn]);
        accv[0][tn] = MFMA_BF16(a0, bv, accv[0][tn]);
        accv[1][tn] = MFMA_BF16(a1, bv, accv[1][tn]);
      }
      __syncthreads();
    }

    // ---- epilogue: kw=exp(k), kwv=kw*v, transpose 32-c chunks via LDS ----
    const int b = (m_blk * 128) >> 11;        // batch
    const int t0 = (m_blk * 128) & 2047;      // token offset within batch
#pragma unroll
    for (int ci = 0; ci < 4; ++ci) {
#pragma unroll
      for (int tm = 0; tm < 2; ++tm)
#pragma unroll
        for (int h = 0; h < 2; ++h) {
          int tn = 2 * ci + h;
          int cl = h * 16 + l15;
          int tl = wave * 32 + tm * 16 + quad * 4;
#pragma unroll
          for (int r = 0; r < 4; ++r) {
            float kw = __expf(acck[tm][tn][r]);
            Lk[cl * 136 + tl + r] = (bf16_t)kw;
            Lv[cl * 136 + tl + r] = (bf16_t)(kw * accv[tm][tn][r]);
          }
        }
      __syncthreads();
      {
        int row = tid >> 3;               // 0..31 (c within chunk)
        int col = (tid & 7) * 16;         // 0..112 (t)
        int c = c_loc + ci * 32 + row;
        size_t g = ((size_t)b * 512 + c) * 2048 + t0 + col;
        *(bf16x8*)&kwT[g] = *(const bf16x8*)&Lk[row * 136 + col];
        *(bf16x8*)&kwT[g + 8] = *(const bf16x8*)&Lk[row * 136 + col + 8];
        *(bf16x8*)&kwvT[g] = *(const bf16x8*)&Lv[row * 136 + col];
        *(bf16x8*)&kwvT[g + 8] = *(const bf16x8*)&Lv[row * 136 + col + 8];
      }
      __syncthreads();
    }
  }
}

// ---------------- dwT[b,j,i] = bf16(exp(-alpha*11*dis[b,i,j])) ----------------
__global__ __launch_bounds__(256) void make_dwT(const float* __restrict__ dis,
                                                bf16_t* __restrict__ dwT,
                                                const float* __restrict__ alpha) {
  __shared__ bf16_t t[64 * 65];
  const float coef = -alpha[0] * 11.0f;  // log2(2048) == 11
  const int j0 = blockIdx.x * 64, i0 = blockIdx.y * 64, b = blockIdx.z;
  const int tid = threadIdx.x;
  const int rr = tid >> 4, cc = (tid & 15) * 4;
#pragma unroll
  for (int p = 0; p < 4; ++p) {
    int i = rr + p * 16;
    f32x4 d = *(const f32x4*)&dis[((size_t)(b * 2048 + i0 + i)) * 2048 + j0 + cc];
#pragma unroll
    for (int e = 0; e < 4; ++e) t[(cc + e) * 65 + i] = (bf16_t)__expf(coef * d[e]);
  }
  __syncthreads();
#pragma unroll
  for (int p = 0; p < 4; ++p) {
    int j = rr + p * 16;
    bf16x4 o;
#pragma unroll
    for (int e = 0; e < 4; ++e) o[e] = t[j * 65 + cc + e];
    *(bf16x4*)&dwT[((size_t)(b * 2048 + j0 + j)) * 2048 + i0 + cc] = o;
  }
}

// ---------------- main batched GEMM + fused epilogue ----------------
// Linear grid, XCD-swizzled: i = m*64 + cb*8 + b  =>  xcd(i%8)=b  => per-XCD
// B working set = one batch's kwT/kwvT tiles (4 MB, fits L2); A tile re-read
// across cb stays L2-hot.
// Per block: C[j, n], n<64 -> w1 (kwvT rows), n>=64 -> w2 (kwT rows).
// out[b,j,c] = qs[b,j,c] * w1/w2  (qs lives in `out` already).
__global__ __launch_bounds__(256) void main_gemm(const bf16_t* __restrict__ dwT,
                                                 const bf16_t* __restrict__ kwvT,
                                                 const bf16_t* __restrict__ kwT,
                                                 float* __restrict__ out) {
  __shared__ bf16_t As[128 * 32];
  __shared__ bf16_t Bs[128 * 32];
  const int K = 2048;
  const int tid = threadIdx.x;
  const int wave = tid >> 6, lane = tid & 63;
  const int lrow = lane >> 2, lk = (lane & 3) * 8;
  const int l15 = lane & 15, quad = lane >> 4;
  const int i = blockIdx.x;
  const int b = i & 7, cb = (i >> 3) & 7, m_blk = i >> 6;

  const bf16_t* Ab = dwT + ((size_t)b * 2048 + m_blk * 128) * K;
  const bf16_t* B1 = kwvT + ((size_t)b * 512 + cb * 64) * K;
  const bf16_t* B2 = kwT + ((size_t)b * 512 + cb * 64) * K;

  f32x4 acc[2][8];
#pragma unroll
  for (int x = 0; x < 2; ++x)
#pragma unroll
    for (int j = 0; j < 8; ++j) acc[x][j] = (f32x4){0.f, 0.f, 0.f, 0.f};

  for (int k0 = 0; k0 < K; k0 += 32) {
#pragma unroll
    for (int s = 0; s < 2; ++s) {
      int row = wave * 32 + s * 16 + lrow;
      async_ld16(Ab + (size_t)row * K + k0 + lk, &As[(wave * 32 + s * 16) * 32]);
      const bf16_t* bsrc = (row < 64) ? (B1 + (size_t)row * K) : (B2 + (size_t)(row - 64) * K);
      async_ld16(bsrc + k0 + lk, &Bs[(wave * 32 + s * 16) * 32]);
    }
    __syncthreads();
    bf16x8 a0 = *(const bf16x8*)&As[(wave * 32 + l15) * 32 + quad * 8];
    bf16x8 a1 = *(const bf16x8*)&As[(wave * 32 + 16 + l15) * 32 + quad * 8];
#pragma unroll
    for (int tn = 0; tn < 8; ++tn) {
      bf16x8 bfr = *(const bf16x8*)&Bs[(tn * 16 + l15) * 32 + quad * 8];
      acc[0][tn] = MFMA_BF16(a0, bfr, acc[0][tn]);
      acc[1][tn] = MFMA_BF16(a1, bfr, acc[1][tn]);
    }
    __syncthreads();
  }

#pragma unroll
  for (int tm = 0; tm < 2; ++tm) {
#pragma unroll
    for (int tc = 0; tc < 4; ++tc) {
      f32x4 w1 = acc[tm][tc];
      f32x4 w2 = acc[tm][tc + 4];
      int c = cb * 64 + tc * 16 + l15;
#pragma unroll
      for (int r = 0; r < 4; ++r) {
        int j = m_blk * 128 + wave * 32 + tm * 16 + quad * 4 + r;
        size_t idx = ((size_t)b * 2048 + j) * 512 + c;
        float sq = out[idx];  // sigmoid(q), written by proj_gemm
        out[idx] = sq * (w1[r] / w2[r]);
      }
    }
  }
}

extern "C" void kernel_launch(void* const* d_in, const int* in_sizes, int n_in,
                              void* d_out, int out_size, void* d_ws, size_t ws_size,
                              hipStream_t stream) {
  const float* x = (const float*)d_in[0];
  const float* dis = (const float*)d_in[1];
  const float* Wq = (const float*)d_in[2];
  const float* Wk = (const float*)d_in[3];
  const float* Wv = (const float*)d_in[4];
  const float* alpha = (const float*)d_in[5];
  float* out = (float*)d_out;

  char* p = (char*)d_ws;
  bf16_t* x_bf = (bf16_t*)p;  p += (size_t)16384 * 512 * 2;       // 16 MB
  bf16_t* Wall = (bf16_t*)p;  p += (size_t)1536 * 512 * 2;        // 1.5 MB
  bf16_t* kwT  = (bf16_t*)p;  p += (size_t)8 * 512 * 2048 * 2;    // 16 MB
  bf16_t* kwvT = (bf16_t*)p;  p += (size_t)8 * 512 * 2048 * 2;    // 16 MB
  bf16_t* dwT  = (bf16_t*)p;  p += (size_t)8 * 2048 * 2048 * 2;   // 64 MB
  if ((size_t)(p - (char*)d_ws) > ws_size) return;  // ws too small: fail visibly

  cvt_bf16_k<<<8192, 256, 0, stream>>>(x, x_bf, 2097152);
  cvt_bf16_k<<<256, 256, 0, stream>>>(Wq, Wall, 65536);
  cvt_bf16_k<<<256, 256, 0, stream>>>(Wk, Wall + 262144, 65536);
  cvt_bf16_k<<<256, 256, 0, stream>>>(Wv, Wall + 524288, 65536);
  proj_gemm<<<dim3(128, 8), 256, 0, stream>>>(x_bf, Wall, out, kwT, kwvT);
  make_dwT<<<dim3(32, 32, 8), 256, 0, stream>>>(dis, dwT, alpha);
  main_gemm<<<1024, 256, 0, stream>>>(dwT, kwvT, kwT, out);
}

// Round 4
// 358.893 us; speedup vs baseline: 1.2013x; 1.1326x over previous
//
#include <hip/hip_runtime.h>
#include <math.h>
#include <stdint.h>

// Problem constants: B=8, N=2048, D=512, H=16, dk=32
// q = x@Wq^T; k = x@Wk^T; v = x@Wv^T            [t=16384, c=512]
// dw[b,i,j] = exp(-alpha*11*dis[b,i,j])
// w1[b,j,c] = sum_i dw[b,i,j]*exp(k)[b,i,c]*v[b,i,c]
// w2[b,j,c] = sum_i dw[b,i,j]*exp(k)[b,i,c]
// out[b,j,c] = sigmoid(q)[b,j,c] * w1/w2

typedef __bf16 bf16_t;
typedef __attribute__((ext_vector_type(4))) __bf16 bf16x4;
typedef __attribute__((ext_vector_type(8))) __bf16 bf16x8;
typedef __attribute__((ext_vector_type(4))) float f32x4;

#define MFMA_BF16(a, b, c) __builtin_amdgcn_mfma_f32_16x16x32_bf16((a), (b), (c), 0, 0, 0)

static __device__ __forceinline__ void async_ld16(const bf16_t* g, bf16_t* lds) {
  __builtin_amdgcn_global_load_lds(
      reinterpret_cast<__attribute__((address_space(1))) unsigned int*>(
          reinterpret_cast<uintptr_t>(g)),
      reinterpret_cast<__attribute__((address_space(3))) unsigned int*>(
          reinterpret_cast<uintptr_t>(lds)),
      16, 0, 0);
}

// Stage ROWS x BK bf16 tile, XOR-swizzled: row r's 16B chunk at position p holds
// global chunk p ^ ((r>>1)&3). Swizzle applied via per-lane source address.
template <int BK, int ROWS>
static __device__ __forceinline__ void stage(const bf16_t* g, int ldg, bf16_t* lds,
                                             int wv, int lane) {
  constexpr int CH = BK / 8;       // 16B chunks per row
  constexpr int RPW = 64 / CH;     // rows per wave-step
  const int r_in = lane / CH;
  const int cpos = lane % CH;
#pragma unroll
  for (int s = 0; s < ROWS / (RPW * 4); ++s) {
    int rbase = wv * (ROWS / 4) + s * RPW;
    int row = rbase + r_in;
    int cg = cpos ^ ((row >> 1) & 3);
    async_ld16(g + (size_t)row * ldg + cg * 8, lds + rbase * BK + lane * 8);
  }
}

// Swizzled fragment read. row16 must be a multiple of 16.
template <int BK>
static __device__ __forceinline__ bf16x8 frag_read(const bf16_t* lds, int row16,
                                                   int l15, int quad, int kc) {
  int p = (quad ^ ((l15 >> 1) & 3)) + kc * 4;
  return *(const bf16x8*)&lds[(row16 + l15) * BK + p * 8];
}

// ---------------- fused fp32 -> bf16 conversion ----------------
// x: 2097152 f32x4; Wq/Wk/Wv: 65536 f32x4 each; total 2293760.
__global__ __launch_bounds__(256) void cvt_all(const float* __restrict__ x,
                                               const float* __restrict__ wq,
                                               const float* __restrict__ wk,
                                               const float* __restrict__ wv,
                                               bf16_t* __restrict__ xb,
                                               bf16_t* __restrict__ wall) {
  int i = blockIdx.x * 256 + threadIdx.x;  // f32x4 index
  if (i >= 2293760) return;
  const float* src;
  bf16_t* dst;
  int off;
  if (i < 2097152) {
    src = x; dst = xb; off = i;
  } else {
    int j = i - 2097152;
    int sel = j >> 16;        // 65536 f32x4 per weight
    off = j & 65535;
    src = (sel == 0) ? wq : (sel == 1) ? wk : wv;
    dst = wall + (size_t)sel * 262144;
  }
  f32x4 f = ((const f32x4*)src)[off];
  bf16x4 o;
  o[0] = (bf16_t)f[0]; o[1] = (bf16_t)f[1]; o[2] = (bf16_t)f[2]; o[3] = (bf16_t)f[3];
  ((bf16x4*)dst)[off] = o;
}

// ---------------- fused projection GEMM ----------------
// n_blk 0..3:  q, 128-wide tile -> sigmoid -> qs_bf (bf16).
// n_blk 4..11: k & v, 64-wide tile -> kw=exp(k), kwv=kw*v -> LDS transpose ->
//              kwT[b,c,t], kwvT[b,c,t] bf16 (main-GEMM operand layout).
__global__ __launch_bounds__(256, 4) void proj_gemm(const bf16_t* __restrict__ A,
                                                    const bf16_t* __restrict__ W,
                                                    bf16_t* __restrict__ qs,
                                                    bf16_t* __restrict__ kwT,
                                                    bf16_t* __restrict__ kwvT) {
  __shared__ __align__(16) char pool[17408];
  bf16_t* As = (bf16_t*)pool;                    // 128x32 = 8 KB
  const int K = 512;
  const int tid = threadIdx.x;
  const int wv = tid >> 6, lane = tid & 63;
  const int l15 = lane & 15, quad = lane >> 4;
  const int m_blk = blockIdx.x, n_blk = blockIdx.y;
  const int wm = wv >> 1, wn = wv & 1;
  const bf16_t* Am = A + (size_t)(m_blk * 128) * K;

  if (n_blk < 4) {
    // ---- q path: 128x128 tile, 64x64 wave tiles ----
    bf16_t* Bsq = (bf16_t*)(pool + 8192);        // 128x32 = 8 KB
    const int c_loc = n_blk * 128;
    f32x4 acc[4][4];
#pragma unroll
    for (int a = 0; a < 4; ++a)
#pragma unroll
      for (int b = 0; b < 4; ++b) acc[a][b] = (f32x4){0.f, 0.f, 0.f, 0.f};

    for (int k0 = 0; k0 < K; k0 += 32) {
      stage<32, 128>(Am + k0, K, As, wv, lane);
      stage<32, 128>(W + (size_t)c_loc * K + k0, K, Bsq, wv, lane);
      __syncthreads();
      bf16x8 a[4], bb[4];
#pragma unroll
      for (int mf = 0; mf < 4; ++mf) a[mf] = frag_read<32>(As, wm * 64 + mf * 16, l15, quad, 0);
#pragma unroll
      for (int nf = 0; nf < 4; ++nf) bb[nf] = frag_read<32>(Bsq, wn * 64 + nf * 16, l15, quad, 0);
#pragma unroll
      for (int mf = 0; mf < 4; ++mf)
#pragma unroll
        for (int nf = 0; nf < 4; ++nf) acc[mf][nf] = MFMA_BF16(a[mf], bb[nf], acc[mf][nf]);
      __syncthreads();
    }
#pragma unroll
    for (int mf = 0; mf < 4; ++mf)
#pragma unroll
      for (int nf = 0; nf < 4; ++nf) {
        int c = c_loc + wn * 64 + nf * 16 + l15;
#pragma unroll
        for (int r = 0; r < 4; ++r) {
          int t = m_blk * 128 + wm * 64 + mf * 16 + quad * 4 + r;
          qs[(size_t)t * 512 + c] = (bf16_t)(1.0f / (1.0f + __expf(-acc[mf][nf][r])));
        }
      }
  } else {
    // ---- kv path: 128x64 tile, 64x32 wave tiles, k and v share A staging ----
    bf16_t* Bk = (bf16_t*)(pool + 8192);         // 64x32 = 4 KB
    bf16_t* Bv = (bf16_t*)(pool + 12288);        // 64x32 = 4 KB
    const int c_loc = (n_blk - 4) * 64;
    f32x4 acck[4][2], accv[4][2];
#pragma unroll
    for (int a = 0; a < 4; ++a)
#pragma unroll
      for (int b = 0; b < 2; ++b) {
        acck[a][b] = (f32x4){0.f, 0.f, 0.f, 0.f};
        accv[a][b] = (f32x4){0.f, 0.f, 0.f, 0.f};
      }
    const bf16_t* Wk = W + (size_t)(512 + c_loc) * K;
    const bf16_t* Wv = W + (size_t)(1024 + c_loc) * K;

    for (int k0 = 0; k0 < K; k0 += 32) {
      stage<32, 128>(Am + k0, K, As, wv, lane);
      stage<32, 64>(Wk + k0, K, Bk, wv, lane);
      stage<32, 64>(Wv + k0, K, Bv, wv, lane);
      __syncthreads();
      bf16x8 a[4], bk[2], bv[2];
#pragma unroll
      for (int mf = 0; mf < 4; ++mf) a[mf] = frag_read<32>(As, wm * 64 + mf * 16, l15, quad, 0);
#pragma unroll
      for (int nf = 0; nf < 2; ++nf) {
        bk[nf] = frag_read<32>(Bk, wn * 32 + nf * 16, l15, quad, 0);
        bv[nf] = frag_read<32>(Bv, wn * 32 + nf * 16, l15, quad, 0);
      }
#pragma unroll
      for (int mf = 0; mf < 4; ++mf)
#pragma unroll
        for (int nf = 0; nf < 2; ++nf) {
          acck[mf][nf] = MFMA_BF16(a[mf], bk[nf], acck[mf][nf]);
          accv[mf][nf] = MFMA_BF16(a[mf], bv[nf], accv[mf][nf]);
        }
      __syncthreads();
    }

    // epilogue: exp/mul + 32-c-chunk transpose through aliased LDS
    bf16_t* Lk = (bf16_t*)pool;            // 32 x 136 = 8704 B
    bf16_t* Lv = (bf16_t*)(pool + 8704);   // 32 x 136 = 8704 B
    const int bb = m_blk >> 4;             // batch
    const int t0 = (m_blk * 128) & 2047;
#pragma unroll
    for (int ci = 0; ci < 2; ++ci) {
      if (wn == ci) {
#pragma unroll
        for (int mf = 0; mf < 4; ++mf)
#pragma unroll
          for (int nf = 0; nf < 2; ++nf) {
            int cl = nf * 16 + l15;
            int tl = wm * 64 + mf * 16 + quad * 4;
#pragma unroll
            for (int r = 0; r < 4; ++r) {
              float kw = __expf(acck[mf][nf][r]);
              Lk[cl * 136 + tl + r] = (bf16_t)kw;
              Lv[cl * 136 + tl + r] = (bf16_t)(kw * accv[mf][nf][r]);
            }
          }
      }
      __syncthreads();
      {
        int rowt = tid >> 3, colt = (tid & 7) * 16;
        int c = c_loc + ci * 32 + rowt;
        size_t g = ((size_t)bb * 512 + c) * 2048 + t0 + colt;
        *(bf16x8*)&kwT[g] = *(const bf16x8*)&Lk[rowt * 136 + colt];
        *(bf16x8*)&kwT[g + 8] = *(const bf16x8*)&Lk[rowt * 136 + colt + 8];
        *(bf16x8*)&kwvT[g] = *(const bf16x8*)&Lv[rowt * 136 + colt];
        *(bf16x8*)&kwvT[g + 8] = *(const bf16x8*)&Lv[rowt * 136 + colt + 8];
      }
      __syncthreads();
    }
  }
}

// ---------------- dwT[b,j,i] = bf16(exp(-alpha*11*dis[b,i,j])) ----------------
__global__ __launch_bounds__(256) void make_dwT(const float* __restrict__ dis,
                                                bf16_t* __restrict__ dwT,
                                                const float* __restrict__ alpha) {
  __shared__ bf16_t t[64 * 65];
  const float coef = -alpha[0] * 11.0f;  // log2(2048) == 11
  const int j0 = blockIdx.x * 64, i0 = blockIdx.y * 64, b = blockIdx.z;
  const int tid = threadIdx.x;
  const int rr = tid >> 4, cc = (tid & 15) * 4;
#pragma unroll
  for (int p = 0; p < 4; ++p) {
    int i = rr + p * 16;
    f32x4 d = *(const f32x4*)&dis[((size_t)(b * 2048 + i0 + i)) * 2048 + j0 + cc];
#pragma unroll
    for (int e = 0; e < 4; ++e) t[(cc + e) * 65 + i] = (bf16_t)__expf(coef * d[e]);
  }
  __syncthreads();
#pragma unroll
  for (int p = 0; p < 4; ++p) {
    int j = rr + p * 16;
    bf16x4 o;
#pragma unroll
    for (int e = 0; e < 4; ++e) o[e] = t[j * 65 + cc + e];
    *(bf16x4*)&dwT[((size_t)(b * 2048 + j0 + j)) * 2048 + i0 + cc] = o;
  }
}

// ---------------- main batched GEMM + fused epilogue ----------------
// Grid linear, XCD-swizzled: i = m*64 + nb*8 + b -> xcd(i%8)=b, per-XCD B set fits L2.
// Block 128(j) x 128(n): B rows interleaved at staging time as
// [16 kwv c0..15][16 kw c0..15][16 kwv c16..31]... so each wave's n-frag pairs
// (w1,w2) land in adjacent register frags. BK=64, XOR-swizzled LDS, 64x64 wave tiles.
__global__ __launch_bounds__(256, 4) void main_gemm(const bf16_t* __restrict__ dwT,
                                                    const bf16_t* __restrict__ kwvT,
                                                    const bf16_t* __restrict__ kwT,
                                                    const bf16_t* __restrict__ qs,
                                                    float* __restrict__ out) {
  __shared__ bf16_t As[128 * 64];
  __shared__ bf16_t Bs[128 * 64];
  const int K = 2048;
  const int tid = threadIdx.x;
  const int wv = tid >> 6, lane = tid & 63;
  const int l15 = lane & 15, quad = lane >> 4;
  const int i = blockIdx.x;
  const int b = i & 7, nb = (i >> 3) & 7, mb = i >> 6;
  const int wm = wv >> 1, wn = wv & 1;

  const bf16_t* Ab = dwT + ((size_t)b * 2048 + mb * 128) * K;
  const bf16_t* Bv = kwvT + ((size_t)b * 512 + nb * 64) * K;
  const bf16_t* Bk = kwT + ((size_t)b * 512 + nb * 64) * K;
  const int r_in8 = lane >> 3, cpos8 = lane & 7;

  f32x4 acc[4][4];
#pragma unroll
  for (int a = 0; a < 4; ++a)
#pragma unroll
    for (int c = 0; c < 4; ++c) acc[a][c] = (f32x4){0.f, 0.f, 0.f, 0.f};

  for (int k0 = 0; k0 < K; k0 += 64) {
    stage<64, 128>(Ab + k0, K, As, wv, lane);
    // B staging with row interleave: local row n -> type=(n>>4)&1, c=(n>>5)*16+(n&15)
#pragma unroll
    for (int s = 0; s < 4; ++s) {
      int rbase = wv * 32 + s * 8;
      int row = rbase + r_in8;
      int type = (rbase >> 4) & 1;  // wave-uniform (8-row band never crosses 16)
      int c = ((rbase >> 5) << 4) + (row & 15);
      int cg = cpos8 ^ ((row >> 1) & 3);
      const bf16_t* src = type ? Bk : Bv;
      async_ld16(src + (size_t)c * K + k0 + cg * 8, Bs + rbase * 64 + lane * 8);
    }
    __syncthreads();
#pragma unroll
    for (int kc = 0; kc < 2; ++kc) {
      bf16x8 a[4], bb[4];
#pragma unroll
      for (int mf = 0; mf < 4; ++mf) a[mf] = frag_read<64>(As, wm * 64 + mf * 16, l15, quad, kc);
#pragma unroll
      for (int nf = 0; nf < 4; ++nf) bb[nf] = frag_read<64>(Bs, wn * 64 + nf * 16, l15, quad, kc);
#pragma unroll
      for (int mf = 0; mf < 4; ++mf)
#pragma unroll
        for (int nf = 0; nf < 4; ++nf) acc[mf][nf] = MFMA_BF16(a[mf], bb[nf], acc[mf][nf]);
    }
    __syncthreads();
  }

  // epilogue: nf even = w1 (kwv), nf odd = w2 (kw); pair in registers.
#pragma unroll
  for (int mf = 0; mf < 4; ++mf)
#pragma unroll
    for (int p = 0; p < 2; ++p) {
      f32x4 w1 = acc[mf][2 * p];
      f32x4 w2 = acc[mf][2 * p + 1];
      int c = nb * 64 + (wn * 2 + p) * 16 + l15;
#pragma unroll
      for (int r = 0; r < 4; ++r) {
        int j = mb * 128 + wm * 64 + mf * 16 + quad * 4 + r;
        size_t idx = ((size_t)b * 2048 + j) * 512 + c;
        out[idx] = (float)qs[idx] * (w1[r] / w2[r]);
      }
    }
}

extern "C" void kernel_launch(void* const* d_in, const int* in_sizes, int n_in,
                              void* d_out, int out_size, void* d_ws, size_t ws_size,
                              hipStream_t stream) {
  const float* x = (const float*)d_in[0];
  const float* dis = (const float*)d_in[1];
  const float* Wq = (const float*)d_in[2];
  const float* Wk = (const float*)d_in[3];
  const float* Wv = (const float*)d_in[4];
  const float* alpha = (const float*)d_in[5];
  float* out = (float*)d_out;

  char* p = (char*)d_ws;
  bf16_t* x_bf = (bf16_t*)p;  p += (size_t)16384 * 512 * 2;       // 16 MB
  bf16_t* Wall = (bf16_t*)p;  p += (size_t)1536 * 512 * 2;        // 1.5 MB
  bf16_t* kwT  = (bf16_t*)p;  p += (size_t)8 * 512 * 2048 * 2;    // 16 MB
  bf16_t* kwvT = (bf16_t*)p;  p += (size_t)8 * 512 * 2048 * 2;    // 16 MB
  bf16_t* dwT  = (bf16_t*)p;  p += (size_t)8 * 2048 * 2048 * 2;   // 64 MB
  bf16_t* qs_bf = (bf16_t*)p; p += (size_t)16384 * 512 * 2;       // 16 MB
  if ((size_t)(p - (char*)d_ws) > ws_size) return;  // ws too small: fail visibly

  cvt_all<<<8960, 256, 0, stream>>>(x, Wq, Wk, Wv, x_bf, Wall);
  proj_gemm<<<dim3(128, 12), 256, 0, stream>>>(x_bf, Wall, qs_bf, kwT, kwvT);
  make_dwT<<<dim3(32, 32, 8), 256, 0, stream>>>(dis, dwT, alpha);
  main_gemm<<<1024, 256, 0, stream>>>(dwT, kwvT, kwT, qs_bf, out);
}

// Round 5
// 349.474 us; speedup vs baseline: 1.2337x; 1.0270x over previous
//
#include <hip/hip_runtime.h>
#include <math.h>
#include <stdint.h>

// Problem constants: B=8, N=2048, D=512, H=16, dk=32
// q = x@Wq^T; k = x@Wk^T; v = x@Wv^T            [t=16384, c=512]
// dw[b,i,j] = exp(-alpha*11*dis[b,i,j])
// w1[b,j,c] = sum_i dw[b,i,j]*exp(k)[b,i,c]*v[b,i,c]
// w2[b,j,c] = sum_i dw[b,i,j]*exp(k)[b,i,c]
// out[b,j,c] = sigmoid(q)[b,j,c] * w1/w2

typedef __bf16 bf16_t;
typedef __attribute__((ext_vector_type(4))) __bf16 bf16x4;
typedef __attribute__((ext_vector_type(8))) __bf16 bf16x8;
typedef __attribute__((ext_vector_type(4))) float f32x4;

#define MFMA_BF16(a, b, c) __builtin_amdgcn_mfma_f32_16x16x32_bf16((a), (b), (c), 0, 0, 0)

static __device__ __forceinline__ void async_ld16(const bf16_t* g, bf16_t* lds) {
  __builtin_amdgcn_global_load_lds(
      reinterpret_cast<__attribute__((address_space(1))) unsigned int*>(
          reinterpret_cast<uintptr_t>(g)),
      reinterpret_cast<__attribute__((address_space(3))) unsigned int*>(
          reinterpret_cast<uintptr_t>(lds)),
      16, 0, 0);
}

// Stage ROWS x BK bf16 tile, XOR-swizzled: row r's 16B chunk at position p holds
// global chunk p ^ ((r>>1)&3). Swizzle applied via per-lane source address.
template <int BK, int ROWS>
static __device__ __forceinline__ void stage(const bf16_t* g, int ldg, bf16_t* lds,
                                             int wv, int lane) {
  constexpr int CH = BK / 8;       // 16B chunks per row
  constexpr int RPW = 64 / CH;     // rows per wave-step
  const int r_in = lane / CH;
  const int cpos = lane % CH;
#pragma unroll
  for (int s = 0; s < ROWS / (RPW * 4); ++s) {
    int rbase = wv * (ROWS / 4) + s * RPW;
    int row = rbase + r_in;
    int cg = cpos ^ ((row >> 1) & 3);
    async_ld16(g + (size_t)row * ldg + cg * 8, lds + rbase * BK + lane * 8);
  }
}

// Swizzled fragment read. row16 must be a multiple of 16.
template <int BK>
static __device__ __forceinline__ bf16x8 frag_read(const bf16_t* lds, int row16,
                                                   int l15, int quad, int kc) {
  int p = (quad ^ ((l15 >> 1) & 3)) + kc * 4;
  return *(const bf16x8*)&lds[(row16 + l15) * BK + p * 8];
}

// ---------------- fused fp32 -> bf16 conversion ----------------
// x: 2097152 f32x4; Wq/Wk/Wv: 65536 f32x4 each; total 2293760.
__global__ __launch_bounds__(256) void cvt_all(const float* __restrict__ x,
                                               const float* __restrict__ wq,
                                               const float* __restrict__ wk,
                                               const float* __restrict__ wv,
                                               bf16_t* __restrict__ xb,
                                               bf16_t* __restrict__ wall) {
  int i = blockIdx.x * 256 + threadIdx.x;  // f32x4 index
  if (i >= 2293760) return;
  const float* src;
  bf16_t* dst;
  int off;
  if (i < 2097152) {
    src = x; dst = xb; off = i;
  } else {
    int j = i - 2097152;
    int sel = j >> 16;        // 65536 f32x4 per weight
    off = j & 65535;
    src = (sel == 0) ? wq : (sel == 1) ? wk : wv;
    dst = wall + (size_t)sel * 262144;
  }
  f32x4 f = ((const f32x4*)src)[off];
  bf16x4 o;
  o[0] = (bf16_t)f[0]; o[1] = (bf16_t)f[1]; o[2] = (bf16_t)f[2]; o[3] = (bf16_t)f[3];
  ((bf16x4*)dst)[off] = o;
}

// ---------------- merged projection GEMM + dis-weight transpose ----------------
// 9728 blocks = 19*512. idx%19 < 3 -> proj (1536 blocks); else -> dw (8192 blocks).
// Interleaving overlaps proj's MFMA/VALU with dw's pure HBM streaming.
//
// proj sub -> (m_blk = sub/12, n_blk = sub%12):
//   n_blk 0..3:  q, 128-wide tile -> sigmoid -> qs blocked layout
//                qs[(((b*128+j16)*32+c16)*256 + quad*64 + l15*4 + r)], bf16.
//   n_blk 4..11: k & v, 64-wide tile -> kw=exp(k), kwv=kw*v -> LDS transpose ->
//                kwT[b,c,t], kwvT[b,c,t] bf16 (main-GEMM operand layout).
// dw sub -> (jt = sub&31, it = (sub>>5)&31, b = sub>>10):
//   dwT[b,j,i] = bf16(exp(-alpha*11*dis[b,i,j])), 64x64 LDS transpose.
__global__ __launch_bounds__(256, 4) void proj_dw(const bf16_t* __restrict__ A,
                                                  const bf16_t* __restrict__ W,
                                                  bf16_t* __restrict__ qs,
                                                  bf16_t* __restrict__ kwT,
                                                  bf16_t* __restrict__ kwvT,
                                                  const float* __restrict__ dis,
                                                  bf16_t* __restrict__ dwT,
                                                  const float* __restrict__ alpha) {
  __shared__ __align__(16) char pool[32768];
  const int tid = threadIdx.x;
  const int idx = blockIdx.x;
  const int g19 = idx / 19, r19 = idx % 19;

  if (r19 >= 3) {
    // ---------------- dw path (copied from proven round-4 make_dwT) ----------------
    int sub = g19 * 16 + (r19 - 3);
    int jt = sub & 31, it = (sub >> 5) & 31, b = sub >> 10;
    bf16_t* t = (bf16_t*)pool;  // 64*65*2 = 8320 B
    const float coef = -alpha[0] * 11.0f;  // log2(2048) == 11
    const int j0 = jt * 64, i0 = it * 64;
    const int rr = tid >> 4, cc = (tid & 15) * 4;
#pragma unroll
    for (int p = 0; p < 4; ++p) {
      int i = rr + p * 16;
      f32x4 d = *(const f32x4*)&dis[((size_t)(b * 2048 + i0 + i)) * 2048 + j0 + cc];
#pragma unroll
      for (int e = 0; e < 4; ++e) t[(cc + e) * 65 + i] = (bf16_t)__expf(coef * d[e]);
    }
    __syncthreads();
#pragma unroll
    for (int p = 0; p < 4; ++p) {
      int j = rr + p * 16;
      bf16x4 o;
#pragma unroll
      for (int e = 0; e < 4; ++e) o[e] = t[j * 65 + cc + e];
      *(bf16x4*)&dwT[((size_t)(b * 2048 + j0 + j)) * 2048 + i0 + cc] = o;
    }
    return;
  }

  // ---------------- proj path ----------------
  const int sub = g19 * 3 + r19;
  const int m_blk = sub / 12, n_blk = sub % 12;
  bf16_t* As = (bf16_t*)pool;  // 128x64 = 16 KB
  const int K = 512;
  const int wv = tid >> 6, lane = tid & 63;
  const int l15 = lane & 15, quad = lane >> 4;
  const int wm = wv >> 1, wn = wv & 1;
  const bf16_t* Am = A + (size_t)(m_blk * 128) * K;
  const int b = m_blk >> 4;

  if (n_blk < 4) {
    // ---- q path: 128x128 tile, 64x64 wave tiles, BK=64 ----
    bf16_t* Bsq = (bf16_t*)(pool + 16384);  // 128x64 = 16 KB
    const int c_loc = n_blk * 128;
    f32x4 acc[4][4];
#pragma unroll
    for (int a = 0; a < 4; ++a)
#pragma unroll
      for (int c = 0; c < 4; ++c) acc[a][c] = (f32x4){0.f, 0.f, 0.f, 0.f};

    for (int k0 = 0; k0 < K; k0 += 64) {
      stage<64, 128>(Am + k0, K, As, wv, lane);
      stage<64, 128>(W + (size_t)c_loc * K + k0, K, Bsq, wv, lane);
      __syncthreads();
#pragma unroll
      for (int kc = 0; kc < 2; ++kc) {
        bf16x8 a[4], bb[4];
#pragma unroll
        for (int mf = 0; mf < 4; ++mf) a[mf] = frag_read<64>(As, wm * 64 + mf * 16, l15, quad, kc);
#pragma unroll
        for (int nf = 0; nf < 4; ++nf) bb[nf] = frag_read<64>(Bsq, wn * 64 + nf * 16, l15, quad, kc);
#pragma unroll
        for (int mf = 0; mf < 4; ++mf)
#pragma unroll
          for (int nf = 0; nf < 4; ++nf) acc[mf][nf] = MFMA_BF16(a[mf], bb[nf], acc[mf][nf]);
      }
      __syncthreads();
    }
    // blocked qs store: bf16x4 per (mf,nf)
#pragma unroll
    for (int mf = 0; mf < 4; ++mf)
#pragma unroll
      for (int nf = 0; nf < 4; ++nf) {
        int j16 = (m_blk & 15) * 8 + wm * 4 + mf;
        int c16 = n_blk * 8 + wn * 4 + nf;
        bf16x4 o;
#pragma unroll
        for (int r = 0; r < 4; ++r)
          o[r] = (bf16_t)(1.0f / (1.0f + __expf(-acc[mf][nf][r])));
        size_t off = (((size_t)b * 128 + j16) * 32 + c16) * 256 + quad * 64 + l15 * 4;
        *(bf16x4*)&qs[off] = o;
      }
  } else {
    // ---- kv path: 128x64 tile, 64x32 wave tiles, k and v share A staging, BK=64 ----
    bf16_t* Bk = (bf16_t*)(pool + 16384);  // 64x64 = 8 KB
    bf16_t* Bv = (bf16_t*)(pool + 24576);  // 64x64 = 8 KB
    const int c_loc = (n_blk - 4) * 64;
    f32x4 acck[4][2], accv[4][2];
#pragma unroll
    for (int a = 0; a < 4; ++a)
#pragma unroll
      for (int c = 0; c < 2; ++c) {
        acck[a][c] = (f32x4){0.f, 0.f, 0.f, 0.f};
        accv[a][c] = (f32x4){0.f, 0.f, 0.f, 0.f};
      }
    const bf16_t* Wk = W + (size_t)(512 + c_loc) * K;
    const bf16_t* Wv = W + (size_t)(1024 + c_loc) * K;

    for (int k0 = 0; k0 < K; k0 += 64) {
      stage<64, 128>(Am + k0, K, As, wv, lane);
      stage<64, 64>(Wk + k0, K, Bk, wv, lane);
      stage<64, 64>(Wv + k0, K, Bv, wv, lane);
      __syncthreads();
#pragma unroll
      for (int kc = 0; kc < 2; ++kc) {
        bf16x8 a[4], bk[2], bv[2];
#pragma unroll
        for (int mf = 0; mf < 4; ++mf) a[mf] = frag_read<64>(As, wm * 64 + mf * 16, l15, quad, kc);
#pragma unroll
        for (int nf = 0; nf < 2; ++nf) {
          bk[nf] = frag_read<64>(Bk, wn * 32 + nf * 16, l15, quad, kc);
          bv[nf] = frag_read<64>(Bv, wn * 32 + nf * 16, l15, quad, kc);
        }
#pragma unroll
        for (int mf = 0; mf < 4; ++mf)
#pragma unroll
          for (int nf = 0; nf < 2; ++nf) {
            acck[mf][nf] = MFMA_BF16(a[mf], bk[nf], acck[mf][nf]);
            accv[mf][nf] = MFMA_BF16(a[mf], bv[nf], accv[mf][nf]);
          }
      }
      __syncthreads();
    }

    // epilogue: exp/mul + 32-c-chunk transpose through aliased LDS
    bf16_t* Lk = (bf16_t*)pool;            // 32 x 136 = 8704 B
    bf16_t* Lv = (bf16_t*)(pool + 8704);   // 32 x 136 = 8704 B
    const int t0 = (m_blk * 128) & 2047;
#pragma unroll
    for (int ci = 0; ci < 2; ++ci) {
      if (wn == ci) {
#pragma unroll
        for (int mf = 0; mf < 4; ++mf)
#pragma unroll
          for (int nf = 0; nf < 2; ++nf) {
            int cl = nf * 16 + l15;
            int tl = wm * 64 + mf * 16 + quad * 4;
#pragma unroll
            for (int r = 0; r < 4; ++r) {
              float kw = __expf(acck[mf][nf][r]);
              Lk[cl * 136 + tl + r] = (bf16_t)kw;
              Lv[cl * 136 + tl + r] = (bf16_t)(kw * accv[mf][nf][r]);
            }
          }
      }
      __syncthreads();
      {
        int rowt = tid >> 3, colt = (tid & 7) * 16;
        int c = c_loc + ci * 32 + rowt;
        size_t g = ((size_t)b * 512 + c) * 2048 + t0 + colt;
        *(bf16x8*)&kwT[g] = *(const bf16x8*)&Lk[rowt * 136 + colt];
        *(bf16x8*)&kwT[g + 8] = *(const bf16x8*)&Lk[rowt * 136 + colt + 8];
        *(bf16x8*)&kwvT[g] = *(const bf16x8*)&Lv[rowt * 136 + colt];
        *(bf16x8*)&kwvT[g + 8] = *(const bf16x8*)&Lv[rowt * 136 + colt + 8];
      }
      __syncthreads();
    }
  }
}

// ---------------- main batched GEMM + fused epilogue ----------------
// Grid linear, XCD-swizzled: i = m*64 + nb*8 + b -> xcd(i%8)=b, per-XCD B set fits L2.
// Block 128(j) x 128(n): B rows interleaved at staging time as
// [16 kwv c0..15][16 kw c0..15][16 kwv c16..31]... so each wave's n-frag pairs
// (w1,w2) land in adjacent register frags. BK=64, 64x64 wave tiles.
__global__ __launch_bounds__(256, 4) void main_gemm(const bf16_t* __restrict__ dwT,
                                                    const bf16_t* __restrict__ kwvT,
                                                    const bf16_t* __restrict__ kwT,
                                                    const bf16_t* __restrict__ qs,
                                                    float* __restrict__ out) {
  __shared__ bf16_t As[128 * 64];
  __shared__ bf16_t Bs[128 * 64];
  const int K = 2048;
  const int tid = threadIdx.x;
  const int wv = tid >> 6, lane = tid & 63;
  const int l15 = lane & 15, quad = lane >> 4;
  const int i = blockIdx.x;
  const int b = i & 7, nb = (i >> 3) & 7, mb = i >> 6;
  const int wm = wv >> 1, wn = wv & 1;

  const bf16_t* Ab = dwT + ((size_t)b * 2048 + mb * 128) * K;
  const bf16_t* Bv = kwvT + ((size_t)b * 512 + nb * 64) * K;
  const bf16_t* Bk = kwT + ((size_t)b * 512 + nb * 64) * K;
  const int r_in8 = lane >> 3, cpos8 = lane & 7;

  f32x4 acc[4][4];
#pragma unroll
  for (int a = 0; a < 4; ++a)
#pragma unroll
    for (int c = 0; c < 4; ++c) acc[a][c] = (f32x4){0.f, 0.f, 0.f, 0.f};

  for (int k0 = 0; k0 < K; k0 += 64) {
    stage<64, 128>(Ab + k0, K, As, wv, lane);
    // B staging with row interleave: local row n -> type=(n>>4)&1, c=(n>>5)*16+(n&15)
#pragma unroll
    for (int s = 0; s < 4; ++s) {
      int rbase = wv * 32 + s * 8;
      int row = rbase + r_in8;
      int type = (rbase >> 4) & 1;  // wave-uniform (8-row band never crosses 16)
      int c = ((rbase >> 5) << 4) + (row & 15);
      int cg = cpos8 ^ ((row >> 1) & 3);
      const bf16_t* src = type ? Bk : Bv;
      async_ld16(src + (size_t)c * K + k0 + cg * 8, Bs + rbase * 64 + lane * 8);
    }
    __syncthreads();
#pragma unroll
    for (int kc = 0; kc < 2; ++kc) {
      bf16x8 a[4], bb[4];
#pragma unroll
      for (int mf = 0; mf < 4; ++mf) a[mf] = frag_read<64>(As, wm * 64 + mf * 16, l15, quad, kc);
#pragma unroll
      for (int nf = 0; nf < 4; ++nf) bb[nf] = frag_read<64>(Bs, wn * 64 + nf * 16, l15, quad, kc);
#pragma unroll
      for (int mf = 0; mf < 4; ++mf)
#pragma unroll
        for (int nf = 0; nf < 4; ++nf) acc[mf][nf] = MFMA_BF16(a[mf], bb[nf], acc[mf][nf]);
    }
    __syncthreads();
  }

  // epilogue: nf even = w1 (kwv), nf odd = w2 (kw); pair in registers.
  // qs is in blocked layout [b][j16][c16][quad][l15][r] -> aligned bf16x4 loads.
#pragma unroll
  for (int mf = 0; mf < 4; ++mf)
#pragma unroll
    for (int p = 0; p < 2; ++p) {
      f32x4 w1 = acc[mf][2 * p];
      f32x4 w2 = acc[mf][2 * p + 1];
      int j16 = mb * 8 + wm * 4 + mf;
      int c16 = nb * 4 + wn * 2 + p;
      size_t qoff = (((size_t)b * 128 + j16) * 32 + c16) * 256 + quad * 64 + l15 * 4;
      bf16x4 qv = *(const bf16x4*)&qs[qoff];
      int c = nb * 64 + (wn * 2 + p) * 16 + l15;
#pragma unroll
      for (int r = 0; r < 4; ++r) {
        int j = mb * 128 + wm * 64 + mf * 16 + quad * 4 + r;
        size_t idx = ((size_t)b * 2048 + j) * 512 + c;
        out[idx] = (float)qv[r] * (w1[r] / w2[r]);
      }
    }
}

extern "C" void kernel_launch(void* const* d_in, const int* in_sizes, int n_in,
                              void* d_out, int out_size, void* d_ws, size_t ws_size,
                              hipStream_t stream) {
  const float* x = (const float*)d_in[0];
  const float* dis = (const float*)d_in[1];
  const float* Wq = (const float*)d_in[2];
  const float* Wk = (const float*)d_in[3];
  const float* Wv = (const float*)d_in[4];
  const float* alpha = (const float*)d_in[5];
  float* out = (float*)d_out;

  char* p = (char*)d_ws;
  bf16_t* x_bf = (bf16_t*)p;  p += (size_t)16384 * 512 * 2;       // 16 MB
  bf16_t* Wall = (bf16_t*)p;  p += (size_t)1536 * 512 * 2;        // 1.5 MB
  bf16_t* kwT  = (bf16_t*)p;  p += (size_t)8 * 512 * 2048 * 2;    // 16 MB
  bf16_t* kwvT = (bf16_t*)p;  p += (size_t)8 * 512 * 2048 * 2;    // 16 MB
  bf16_t* dwT  = (bf16_t*)p;  p += (size_t)8 * 2048 * 2048 * 2;   // 64 MB
  bf16_t* qs_bf = (bf16_t*)p; p += (size_t)16384 * 512 * 2;       // 16 MB (blocked layout)
  if ((size_t)(p - (char*)d_ws) > ws_size) return;  // ws too small: fail visibly

  cvt_all<<<8960, 256, 0, stream>>>(x, Wq, Wk, Wv, x_bf, Wall);
  proj_dw<<<9728, 256, 0, stream>>>(x_bf, Wall, qs_bf, kwT, kwvT, dis, dwT, alpha);
  main_gemm<<<1024, 256, 0, stream>>>(dwT, kwvT, kwT, qs_bf, out);
}